// Round 1
// baseline (3242.981 us; speedup 1.0000x reference)
//
#include <hip/hip_runtime.h>

#define HH 64
#define WW 64
#define HWSZ 4096
#define CC 256
#define OO 256
#define PP 32
#define NOUTCH 768
#define OFFCH 166

// Per-block: one branch (K), one batch b, PP consecutive pixels, all 256 output channels.
// Thread t owns output channel o = t with PP fp32 accumulators.
template<int K>
__device__ __forceinline__ void dconv_block(
    const float* __restrict__ feat, const float* __restrict__ offset,
    const float* __restrict__ wt, float* __restrict__ out,
    int b, int p0, int ch_off, int oc_off,
    int* __restrict__ meta_i, float* __restrict__ meta_w, float* __restrict__ s)
{
    constexpr int KK = K * K;
    const int tid = threadIdx.x;

    // ---- 1. Precompute bilinear metadata for (j, p) pairs ----
    for (int idx = tid; idx < KK * PP; idx += 256) {
        const int j = idx / PP;
        const int p = idx - j * PP;
        const int pix = p0 + p;
        const int y = pix >> 6;
        const int x = pix & 63;
        const int obase = ((b * OFFCH + ch_off + 2 * j) * HH + y) * WW + x;
        const float oy = offset[obase];
        const float ox = offset[obase + HWSZ];   // next channel (x-offset)
        const float sy = (float)y + oy;
        const float sx = (float)x + ox;
        const float fy = floorf(sy);
        const float fx = floorf(sx);
        const float dy = sy - fy;
        const float dx = sx - fx;
        const int y0 = (int)fy, x0 = (int)fx;
        const int y1 = y0 + 1,  x1 = x0 + 1;
        const bool vy0 = (y0 >= 0) & (y0 < HH);
        const bool vy1 = (y1 >= 0) & (y1 < HH);
        const bool vx0 = (x0 >= 0) & (x0 < WW);
        const bool vx1 = (x1 >= 0) & (x1 < WW);
        const float w00 = (1.f - dy) * (1.f - dx) * ((vy0 && vx0) ? 1.f : 0.f);
        const float w01 = (1.f - dy) * dx         * ((vy0 && vx1) ? 1.f : 0.f);
        const float w10 = dy * (1.f - dx)         * ((vy1 && vx0) ? 1.f : 0.f);
        const float w11 = dy * dx                 * ((vy1 && vx1) ? 1.f : 0.f);
        const int y0c = min(max(y0, 0), HH - 1);
        const int y1c = min(max(y1, 0), HH - 1);
        const int x0c = min(max(x0, 0), WW - 1);
        const int x1c = min(max(x1, 0), WW - 1);
        meta_i[idx] = y0c | (y1c << 8) | (x0c << 16) | (x1c << 24);
        meta_w[idx * 4 + 0] = w00;
        meta_w[idx * 4 + 1] = w01;
        meta_w[idx * 4 + 2] = w10;
        meta_w[idx * 4 + 3] = w11;
    }

    float acc[PP];
#pragma unroll
    for (int p = 0; p < PP; ++p) acc[p] = 0.f;

    const float* wrow = wt + (size_t)tid * CC * KK;   // w[o=tid][c][j]

    for (int c = 0; c < CC; ++c) {
        __syncthreads();  // meta ready (first iter) / s no longer read (later iters)
        const float* fp = feat + (size_t)(b * CC + c) * HWSZ;
        // ---- 2. Stage sampled values s[j][p] for this channel ----
        for (int idx = tid; idx < KK * PP; idx += 256) {
            const int m = meta_i[idx];
            const int y0c = m & 255;
            const int y1c = (m >> 8) & 255;
            const int x0c = (m >> 16) & 255;
            const int x1c = (m >> 24) & 255;
            const float4 wv = *(const float4*)(meta_w + idx * 4);
            const float v = wv.x * fp[y0c * WW + x0c]
                          + wv.y * fp[y0c * WW + x1c]
                          + wv.z * fp[y1c * WW + x0c]
                          + wv.w * fp[y1c * WW + x1c];
            s[idx] = v;
        }
        __syncthreads();
        // ---- 3. Accumulate: acc[p] += s[j][p] * w[o][c][j] ----
        const float* wc = wrow + c * KK;
        for (int j = 0; j < KK; ++j) {
            const float wv = wc[j];
            const float* sj = s + j * PP;
#pragma unroll
            for (int p = 0; p < PP; ++p) acc[p] += sj[p] * wv;
        }
    }

    // ---- 4. Write out[b][oc_off + tid][p0..p0+PP) ----
    float* op = out + ((size_t)(b * NOUTCH + oc_off + tid)) * HWSZ + p0;
#pragma unroll
    for (int p = 0; p < PP; ++p) op[p] = acc[p];
}

__global__ __launch_bounds__(256)
void mcdc_kernel(const float* __restrict__ feat, const float* __restrict__ offset,
                 const float* __restrict__ w3, const float* __restrict__ w5,
                 const float* __restrict__ w7, float* __restrict__ out)
{
    __shared__ int   meta_i[49 * PP];
    __shared__ float meta_w[49 * PP * 4];
    __shared__ float s[49 * PP];

    const int bid = blockIdx.x;
    const int br  = bid % 3;          // interleave branches across CUs
    const int sub = bid / 3;          // 0..255
    const int b   = sub >> 7;         // 128 pixel-blocks per batch
    const int p0  = (sub & 127) * PP;

    if (br == 0)
        dconv_block<3>(feat, offset, w3, out, b, p0, 0,  0,   meta_i, meta_w, s);
    else if (br == 1)
        dconv_block<5>(feat, offset, w5, out, b, p0, 18, 256, meta_i, meta_w, s);
    else
        dconv_block<7>(feat, offset, w7, out, b, p0, 68, 512, meta_i, meta_w, s);
}

extern "C" void kernel_launch(void* const* d_in, const int* in_sizes, int n_in,
                              void* d_out, int out_size, void* d_ws, size_t ws_size,
                              hipStream_t stream)
{
    const float* feat   = (const float*)d_in[0];
    const float* offset = (const float*)d_in[1];
    const float* w3     = (const float*)d_in[2];
    const float* w5     = (const float*)d_in[3];
    const float* w7     = (const float*)d_in[4];
    float* out = (float*)d_out;

    dim3 grid(768);
    dim3 block(256);
    mcdc_kernel<<<grid, block, 0, stream>>>(feat, offset, w3, w5, w7, out);
}

// Round 2
// 996.501 us; speedup vs baseline: 3.2544x; 3.2544x over previous
//
#include <hip/hip_runtime.h>

using bf16x8 = __attribute__((ext_vector_type(8))) short;
using f32x4  = __attribute__((ext_vector_type(4))) float;

#define HW   4096
#define CIN  256
#define OFFC 166

// ws element offsets (ushort) for fragment-major bf16 weights per branch
#define WS3_BASE 0
#define WS5_BASE 589824
#define WS7_BASE 2228224
#define WS_TOTAL 5439488   // elems; *2 bytes = 10,878,976 B

__device__ __forceinline__ unsigned short f2bf(float f) {
    unsigned u = __builtin_bit_cast(unsigned, f);
    return (unsigned short)((u + 0x7fffu + ((u >> 16) & 1u)) >> 16);   // RNE
}
__device__ __forceinline__ float bf2f(unsigned v) {
    return __builtin_bit_cast(float, v << 16);
}

// ---------------- weight prep: fp32 [o][c][kh][kw] -> bf16 fragment-major ----------------
// layout: ws[base + ((ks*16 + gm)*64 + lane)*8 + e]  holds  w[o = gm*16 + (lane&15)][c][j]
// with k-index r = ks*32 + (lane>>4)*8 + e,  j = r>>8, c = r&255   (j-major K flattening)
__global__ __launch_bounds__(256)
void mcdc_prep(const float* __restrict__ w3, const float* __restrict__ w5,
               const float* __restrict__ w7, unsigned short* __restrict__ ws)
{
    int idx = blockIdx.x * 256 + threadIdx.x;
    const float* src; int KKv, base;
    if (idx < WS5_BASE)      { src = w3; KKv = 9;  base = WS3_BASE; }
    else if (idx < WS7_BASE) { src = w5; KKv = 25; base = WS5_BASE; }
    else                     { src = w7; KKv = 49; base = WS7_BASE; }
    int rel = idx - base;
    int e  = rel & 7;
    int l  = (rel >> 3) & 63;
    int gm = (rel >> 9) & 15;
    int ks = rel >> 13;
    int o  = gm * 16 + (l & 15);
    int r  = ks * 32 + (l >> 4) * 8 + e;
    int j  = r >> 8;
    int c  = r & 255;
    float v = src[((size_t)o * CIN + c) * KKv + j];
    ws[idx] = f2bf(v);
}

// ---------------- fused sample + GEMM ----------------
template<int K, int CH_OFF, int OC_OFF>
__device__ __forceinline__ void dconv(
    const float* __restrict__ feat, const float* __restrict__ off,
    const unsigned short* __restrict__ wsA, float* __restrict__ out,
    int b, int p0,
    unsigned short (&sB)[2][64][40], uint4 (&meta)[2][64])
{
    constexpr int KK = K * K;
    constexpr int NK = KK * 8;          // K_total/32 = KK*256/32
    const int tid  = threadIdx.x;
    const int lane = tid & 63;
    const int wm   = tid >> 6;          // wave id 0..3, owns o in [wm*64, wm*64+64)
    const int sp   = tid >> 2;          // staging pixel 0..63
    const int koct = tid & 3;           // staging k-octet 0..3

    // bilinear meta for tap jn, all 64 pixels of this block (threads 0..63)
    auto computeMeta = [&](int jn) {
        if (tid < 64) {
            const int p = tid, pix = p0 + p;
            const int y = pix >> 6, x = pix & 63;
            const float* ob = off + ((size_t)(b * OFFC + CH_OFF + 2 * jn)) * HW + (y << 6) + x;
            const float oy = ob[0], ox = ob[HW];
            const float sy = (float)y + oy, sx = (float)x + ox;
            const float fy = floorf(sy), fx = floorf(sx);
            const float dy = sy - fy, dx = sx - fx;
            const int y0 = (int)fy, x0 = (int)fx;
            const int y1 = y0 + 1,  x1 = x0 + 1;
            const bool vy0 = (y0 >= 0) & (y0 < 64), vy1 = (y1 >= 0) & (y1 < 64);
            const bool vx0 = (x0 >= 0) & (x0 < 64), vx1 = (x1 >= 0) & (x1 < 64);
            const float w00 = (1.f - dy) * (1.f - dx) * ((vy0 && vx0) ? 1.f : 0.f);
            const float w01 = (1.f - dy) * dx         * ((vy0 && vx1) ? 1.f : 0.f);
            const float w10 = dy * (1.f - dx)         * ((vy1 && vx0) ? 1.f : 0.f);
            const float w11 = dy * dx                 * ((vy1 && vx1) ? 1.f : 0.f);
            const int y0c = min(max(y0, 0), 63), y1c = min(max(y1, 0), 63);
            const int x0c = min(max(x0, 0), 63), x1c = min(max(x1, 0), 63);
            uint4 mm;
            mm.x = (unsigned)(y0c * 64 + x0c) | ((unsigned)(y0c * 64 + x1c) << 16);
            mm.y = (unsigned)(y1c * 64 + x0c) | ((unsigned)(y1c * 64 + x1c) << 16);
            mm.z = (unsigned)f2bf(w00) | ((unsigned)f2bf(w01) << 16);
            mm.w = (unsigned)f2bf(w10) | ((unsigned)f2bf(w11) << 16);
            meta[jn & 1][p] = mm;
        }
    };

    // stage B-tile k-step ks into sB[ks&1]: thread computes 8 s-values (8 c-planes, 1 meta)
    auto stage = [&](int ks) {
        const int j  = ks >> 3;
        const int cb = (ks & 7) * 32 + koct * 8;
        const uint4 mm = meta[j & 1][sp];
        const int i00 = mm.x & 0xffff, i01 = mm.x >> 16;
        const int i10 = mm.y & 0xffff, i11 = mm.y >> 16;
        const float w00 = bf2f(mm.z & 0xffff), w01 = bf2f(mm.z >> 16);
        const float w10 = bf2f(mm.w & 0xffff), w11 = bf2f(mm.w >> 16);
        const float* fp = feat + ((size_t)(b * CIN + cb)) * HW;
        bf16x8 sv;
#pragma unroll
        for (int e = 0; e < 8; ++e) {
            const float v = w00 * fp[i00] + w01 * fp[i01]
                          + w10 * fp[i10] + w11 * fp[i11];
            sv[e] = (short)f2bf(v);
            fp += HW;
        }
        *(bf16x8*)(&sB[ks & 1][sp][koct * 8]) = sv;
    };

    auto loadA = [&](bf16x8 (&a)[4], int ks) {
#pragma unroll
        for (int mf = 0; mf < 4; ++mf)
            a[mf] = *(const bf16x8*)(wsA + (((size_t)ks * 16 + wm * 4 + mf) * 64 + lane) * 8);
    };

    f32x4 acc[4][4];
#pragma unroll
    for (int i = 0; i < 4; ++i)
#pragma unroll
        for (int n = 0; n < 4; ++n) acc[i][n] = f32x4{0.f, 0.f, 0.f, 0.f};

    bf16x8 a_cur[4], a_nxt[4];
    computeMeta(0);
    __syncthreads();
    stage(0);
    loadA(a_cur, 0);

    for (int ks = 0; ks < NK; ++ks) {
        __syncthreads();                       // sB[ks&1] staged; sB[ks&1^1] free
        if (ks + 1 < NK) { stage(ks + 1); loadA(a_nxt, ks + 1); }
        if ((ks & 7) == 6 && ks + 2 < NK) computeMeta((ks + 2) >> 3);

        bf16x8 bfr[4];
        const int cu = ks & 1;
#pragma unroll
        for (int nf = 0; nf < 4; ++nf)
            bfr[nf] = *(const bf16x8*)(&sB[cu][nf * 16 + (lane & 15)][(lane >> 4) * 8]);
#pragma unroll
        for (int nf = 0; nf < 4; ++nf)
#pragma unroll
            for (int mf = 0; mf < 4; ++mf)
                acc[mf][nf] = __builtin_amdgcn_mfma_f32_16x16x32_bf16(
                    a_cur[mf], bfr[nf], acc[mf][nf], 0, 0, 0);
#pragma unroll
        for (int mf = 0; mf < 4; ++mf) a_cur[mf] = a_nxt[mf];
    }

    // epilogue: D frag layout col=lane&15, row=(lane>>4)*4+r  [m89-verified]
#pragma unroll
    for (int mf = 0; mf < 4; ++mf) {
#pragma unroll
        for (int nf = 0; nf < 4; ++nf) {
#pragma unroll
            for (int r = 0; r < 4; ++r) {
                const int o = wm * 64 + mf * 16 + (lane >> 4) * 4 + r;
                const int p = nf * 16 + (lane & 15);
                out[((size_t)(b * 768 + OC_OFF + o)) * HW + p0 + p] = acc[mf][nf][r];
            }
        }
    }
}

__global__ __launch_bounds__(256)
void mcdc_main(const float* __restrict__ feat, const float* __restrict__ off,
               const unsigned short* __restrict__ ws, float* __restrict__ out)
{
    __shared__ __attribute__((aligned(16))) unsigned short sB[2][64][40];
    __shared__ uint4 meta[2][64];

    const int bid = blockIdx.x;
    int br, pb;
    if (bid < 128)      { br = 2; pb = bid; }        // k=7 first (heaviest)
    else if (bid < 256) { br = 1; pb = bid - 128; }
    else                { br = 0; pb = bid - 256; }
    const int b  = pb >> 6;
    const int p0 = (pb & 63) << 6;

    if (br == 2)      dconv<7, 68, 512>(feat, off, ws + WS7_BASE, out, b, p0, sB, meta);
    else if (br == 1) dconv<5, 18, 256>(feat, off, ws + WS5_BASE, out, b, p0, sB, meta);
    else              dconv<3, 0,  0  >(feat, off, ws + WS3_BASE, out, b, p0, sB, meta);
}

extern "C" void kernel_launch(void* const* d_in, const int* in_sizes, int n_in,
                              void* d_out, int out_size, void* d_ws, size_t ws_size,
                              hipStream_t stream)
{
    const float* feat = (const float*)d_in[0];
    const float* off  = (const float*)d_in[1];
    const float* w3   = (const float*)d_in[2];
    const float* w5   = (const float*)d_in[3];
    const float* w7   = (const float*)d_in[4];
    float* out = (float*)d_out;
    unsigned short* ws = (unsigned short*)d_ws;

    if (ws_size < (size_t)WS_TOTAL * 2) return;   // loud failure (output stays poisoned)

    mcdc_prep<<<dim3(WS_TOTAL / 256), dim3(256), 0, stream>>>(w3, w5, w7, ws);
    mcdc_main<<<dim3(384), dim3(256), 0, stream>>>(feat, off, ws, out);
}